// Round 5
// baseline (147.495 us; speedup 1.0000x reference)
//
#include <hip/hip_runtime.h>
#include <math.h>

// AntiAliasInterpolation2d: 13x13 separable gaussian blur (sigma=1.5, zero-pad 6)
// + nearest 4x downsample, fused. x: (32,512,512,3) f32 -> out: (32,128,128,3) f32.
//
// out[n,i,j,c] = sum_{dy,dx} w[dy]*w[dx] * x[n, 4i+dy, 4j+dx, c]
//
// R5 vs R4:
//  (1) ONE barrier per block: all 8 vertically-blurred rows staged in LDS
//      (8 planes x 3 ch x PITCH = 51 KB, 2 blocks/CU), vertical phase is an
//      unbroken 41-row load+FMA stream, horizontal phase a pure LDS tail.
//  (2) XCD swizzle: 4 adjacent bands of one image share an XCD (g%8
//      round-robin heuristic) so band-halo rows (~9 shared rows/pair) hit L2
//      instead of re-fetching HBM.
// Vertical conv runs straight from global float4 loads into rolling float4
// accumulators (rows in quads y=4q+p; phase p feeds output rows q-1..q+2 with
// static weights; fully unrolled -> rotations are SSA renames, dead rows pruned).

namespace {
constexpr int N_IMG   = 32;
constexpr int H_IN    = 512;
constexpr int W_IN    = 512;
constexpr int C_CH    = 3;
constexpr int H_OUT   = 128;
constexpr int W_OUT   = 128;
constexpr int T_ROWS  = 8;                     // output rows per block
constexpr int BANDS   = H_OUT / T_ROWS;        // 16
constexpr int PITCH   = 532;                   // 8 front halo + 512 + pad, %4==0
constexpr int ROW_ELEMS = W_IN * C_CH;         // 1536
constexpr int NTHREADS = 384;                  // thread t owns flat floats 4t..4t+3
constexpr int LDS_FLOATS = T_ROWS * 3 * PITCH; // 8 rows x 3 channel planes (51 KB)
}

__device__ __forceinline__ float4 f4fma(float w, const float4& p, const float4& a) {
  return make_float4(fmaf(w, p.x, a.x), fmaf(w, p.y, a.y),
                     fmaf(w, p.z, a.z), fmaf(w, p.w, a.w));
}

__global__ __launch_bounds__(NTHREADS, 2)
void aa_blur_down(const float* __restrict__ in, float* __restrict__ out) {
  __shared__ __align__(16) float lds[LDS_FLOATS];

  const int tid = threadIdx.x;
  const int j   = tid / 3;                     // output column 0..127
  const int c   = tid % 3;                     // channel

  // XCD swizzle: blocks with equal (blockIdx%8) land on the same XCD
  // (round-robin heuristic). Map so 4 adjacent bands of one image share XCD.
  const int g    = blockIdx.x;                 // 0..511
  const int low3 = g & 7;
  const int t8   = g >> 3;                     // 0..63
  const int m4   = t8 & 3;                     // member within band-group
  const int G    = ((t8 >> 2) << 3) | low3;    // group id 0..127
  const int n    = G >> 2;                     // image 0..31
  const int band = ((G & 3) << 2) | m4;        // 0..15
  const int i0   = band * T_ROWS;

  // normalized 1D gaussian weights (13 taps), static use -> registers
  float wt[13];
  {
    float s = 0.f;
#pragma unroll
    for (int r = 0; r < 13; ++r) {
      const float d = (float)r - 6.0f;
      wt[r] = expf(-d * d * (1.0f / 4.5f));
      s += wt[r];
    }
    const float inv = 1.0f / s;
#pragma unroll
    for (int r = 0; r < 13; ++r) wt[r] *= inv;
  }

  const int qstart = i0 - 2;                   // quads qstart..qstart+10
  const float* img = in + (size_t)n * H_IN * ROW_ELEMS;

  // zero ONLY the halo floats: per plane-row, padded [0,8) and [520,524).
  // 24 plane-rows x 12 floats = 288; threads 0..287 write one each. These are
  // covered by the single barrier below and never overwritten.
  if (tid < 24 * 12) {
    const int r = tid / 12, o = tid % 12;
    lds[r * PITCH + (o < 8 ? o : 512 + o)] = 0.f;
  }

  // planar scatter offsets for this thread's float4 (flat e=4t+k: c=e%3, x=e/3)
  int off_e[4];
#pragma unroll
  for (int e = 0; e < 4; ++e) {
    const int ce = c + e;
    const int cc = (ce >= 3) ? ce - 3 : ce;
    const int xx = (4 * tid) / 3 + ((ce >= 3) ? 1 : 0);
    off_e[e] = cc * PITCH + xx + 8;
  }

  // ring-of-3 staging, distance-2 prefetch; statically-dead rows pruned
  float4 P[3][4];
  auto loadq = [&](int slot, int s) {
    const int q = qstart + s;
#pragma unroll
    for (int m = 0; m < 4; ++m) {
      const bool dead = (s == 0 && m < 2) || (s == 10 && m == 3);
      const int y = 4 * q + m;
      if (!dead && (unsigned)y < (unsigned)H_IN) {
        P[slot][m] = reinterpret_cast<const float4*>(img + (size_t)y * ROW_ELEMS)[tid];
      } else {
        P[slot][m] = make_float4(0.f, 0.f, 0.f, 0.f);
      }
    }
  };

  float4 A0 = make_float4(0,0,0,0), A1 = A0, A2 = A0, A3 = A0;

  loadq(0, 0);
  loadq(1, 1);

  // ---- vertical phase: no barriers, one long load+FMA stream ----
#pragma unroll
  for (int s = 0; s <= 10; ++s) {
    if (s + 2 <= 10) loadq((s + 2) % 3, s + 2);

    const float4 p0 = P[s % 3][0];
    const float4 p1 = P[s % 3][1];
    const float4 p2 = P[s % 3][2];
    const float4 p3 = P[s % 3][3];

    if (s >= 3)           { A0 = f4fma(wt[10], p0, A0); A0 = f4fma(wt[11], p1, A0); A0 = f4fma(wt[12], p2, A0); }
    if (s >= 2 && s <= 9) { A1 = f4fma(wt[6],  p0, A1); A1 = f4fma(wt[7],  p1, A1); A1 = f4fma(wt[8],  p2, A1); A1 = f4fma(wt[9], p3, A1); }
    if (s >= 1 && s <= 8) { A2 = f4fma(wt[2],  p0, A2); A2 = f4fma(wt[3],  p1, A2); A2 = f4fma(wt[4],  p2, A2); A2 = f4fma(wt[5], p3, A2); }
    if (s <= 7)           { A3 = f4fma(wt[0],  p2, A3); A3 = f4fma(wt[1],  p3, A3); }

    if (s >= 3) {
      float* buf = &lds[(s - 3) * 3 * PITCH];  // blurred row i0+(s-3)
      buf[off_e[0]] = A0.x;
      buf[off_e[1]] = A0.y;
      buf[off_e[2]] = A0.z;
      buf[off_e[3]] = A0.w;
    }
    A0 = A1; A1 = A2; A2 = A3; A3 = make_float4(0.f, 0.f, 0.f, 0.f);
  }

  __syncthreads();                             // the ONE barrier

  // ---- horizontal phase: pure LDS reads + coalesced stores ----
#pragma unroll
  for (int r = 0; r < T_ROWS; ++r) {
    const float* buf = &lds[r * 3 * PITCH];
    // padded window [4j, 4j+16), taps at [2..14]
    const float4* pl = reinterpret_cast<const float4*>(&buf[c * PITCH + 4 * j]);
    const float4 wa = pl[0];
    const float4 wb = pl[1];
    const float4 wc = pl[2];
    const float4 wd = pl[3];
    float hh;
    hh = wt[0] * wa.z;
    hh = fmaf(wt[1],  wa.w, hh);
    hh = fmaf(wt[2],  wb.x, hh);
    hh = fmaf(wt[3],  wb.y, hh);
    hh = fmaf(wt[4],  wb.z, hh);
    hh = fmaf(wt[5],  wb.w, hh);
    hh = fmaf(wt[6],  wc.x, hh);
    hh = fmaf(wt[7],  wc.y, hh);
    hh = fmaf(wt[8],  wc.z, hh);
    hh = fmaf(wt[9],  wc.w, hh);
    hh = fmaf(wt[10], wd.x, hh);
    hh = fmaf(wt[11], wd.y, hh);
    hh = fmaf(wt[12], wd.z, hh);
    out[(size_t)(n * H_OUT + i0 + r) * (W_OUT * C_CH) + tid] = hh;
  }
}

extern "C" void kernel_launch(void* const* d_in, const int* in_sizes, int n_in,
                              void* d_out, int out_size, void* d_ws, size_t ws_size,
                              hipStream_t stream) {
  const float* x = (const float*)d_in[0];
  float* out = (float*)d_out;
  (void)in_sizes; (void)n_in; (void)out_size; (void)d_ws; (void)ws_size;
  hipLaunchKernelGGL(aa_blur_down, dim3(N_IMG * BANDS), dim3(NTHREADS), 0, stream, x, out);
}